// Round 13
// baseline (2360.014 us; speedup 1.0000x reference)
//
#include <hip/hip_runtime.h>
#include <math.h>

#define B_ 64
#define T_ 512
#define H_ 1024
#define V_ 256
#define O_ 1024
#define KFC 2048

typedef short bf16x8 __attribute__((ext_vector_type(8)));
typedef _Float16 f16x8 __attribute__((ext_vector_type(8)));
typedef float f32x4 __attribute__((ext_vector_type(4)));
typedef int   i32x4 __attribute__((ext_vector_type(4)));
typedef unsigned long long u64x2 __attribute__((ext_vector_type(2)));

#define FLIP64 0x8000800080008000ULL

// ---- workspace layout (bytes) ----
#define OFF_TABLE_F 0                 // [V][H] f32 (W_ih^T + b_ih + b_hh), fwd
#define OFF_TABLE_B 1048576           // same, bwd
#define OFF_XT      2097152           // [T][B] i32 (transposed x)
#define OFF_WHH     2228224           // fp16 [d][tt64][kt32][lane64][8] (4 MB)
#define OFF_WFC     6422528           // fp16 [ob][k32][nt][lane][8] (4 MB)
#define OFF_HSF     10616832          // fp16 frag, sign-flipped: [t][bt][kt][q][lane'] u64 (64 MB)
#define OFF_HSB     77725696          // same, bwd (64 MB)  — adjacent to HSF

__device__ __forceinline__ float fast_tanh(float zz) {
  float e = __expf(2.0f * zz);
  return 1.0f - 2.0f * __builtin_amdgcn_rcpf(e + 1.0f);
}

// ---------------- prep: tables, transposes, packed weights, hs zeroing ----------------
__global__ void prep_kernel(const int* __restrict__ x,
    const float* __restrict__ WihF, const float* __restrict__ WhhF,
    const float* __restrict__ bihF, const float* __restrict__ bhhF,
    const float* __restrict__ WihB, const float* __restrict__ WhhB,
    const float* __restrict__ bihB, const float* __restrict__ bhhB,
    const float* __restrict__ Wfc,
    float* __restrict__ tableF, float* __restrict__ tableB,
    int* __restrict__ xT, short* __restrict__ whhpack,
    short* __restrict__ wfcpack, unsigned long long* __restrict__ hsz)
{
  const long NT1 = 524288, NT2 = 32768, NT3 = 2097152, NT4 = 2097152;
  const long NT5 = 16777216;  // zero hsF+hsB (adjacent, 128 MB) as u64
  const long total = NT1 + NT2 + NT3 + NT4 + NT5;
  for (long i = (long)blockIdx.x * blockDim.x + threadIdx.x; i < total;
       i += (long)gridDim.x * blockDim.x) {
    long j = i;
    if (j < NT1) {
      int d = (int)(j >> 18);
      int r = (int)(j & 262143);
      int v = r >> 10, h = r & 1023;
      const float* Wih = d ? WihB : WihF;
      const float* bi  = d ? bihB : bihF;
      const float* bh  = d ? bhhB : bhhF;
      (d ? tableB : tableF)[r] = Wih[h * V_ + v] + bi[h] + bh[h];
      continue;
    }
    j -= NT1;
    if (j < NT2) {
      int t = (int)(j >> 6), bb = (int)(j & 63);
      xT[j] = x[bb * T_ + t];
      continue;
    }
    j -= NT2;
    if (j < NT3) {
      // whhpack [d][tt64][kt32][lane64][8]:
      //   c = tt*16 + (lane&15), k = kt*32 + (lane>>4)*8 + jj
      int d = (int)(j >> 20);
      int r = (int)(j & 1048575);
      int jj = r & 7;
      int lanei = (r >> 3) & 63;
      int kt = (r >> 9) & 31;
      int tt = (r >> 14) & 63;
      int c = tt * 16 + (lanei & 15);
      int k = kt * 32 + (lanei >> 4) * 8 + jj;
      float w = (d ? WhhB : WhhF)[c * H_ + k];
      _Float16 wh = (_Float16)w;
      whhpack[j] = __builtin_bit_cast(short, wh);
      continue;
    }
    j -= NT3;
    if (j < NT4) {
      int jj = (int)(j & 7);
      int lanei = (int)((j >> 3) & 63);
      int nti = (int)((j >> 9) & 3);
      int k32 = (int)((j >> 11) & 63);
      int obi = (int)(j >> 17);
      int o = obi * 64 + nti * 16 + (lanei & 15);
      int k = k32 * 32 + (lanei >> 4) * 8 + jj;
      _Float16 wf = (_Float16)Wfc[(long)o * KFC + k];
      wfcpack[j] = __builtin_bit_cast(short, wf);
      continue;
    }
    j -= NT4;
    hsz[j] = 0ULL;  // unwritten sentinel for the self-signaling exchange
    continue;
  }
}

// ---------------- persistent bidirectional recurrence ----------------
// 64 WGs x 256 thr. WG = (dir, bt 16-row tile, csh 128-col slice); wave = ct,
// owning TWO 16-col tiles (tt0 = csh*8+ct*2, tt1 = tt0+1 -> same kt slot,
// publish offsets pub_off and pub_off+32). Halves chip-wide exchange reads
// (4 -> 2 MB/step) and poll traffic; 32 publishers per (dir,bt) class.
// W read fragment-direct from global (L2-resident; R12-validated mode).
// h exchange: self-signaling fp16 fragment slots (u64 nonzero == written),
// cooperative dedup staging into 32 KB LDS, half-split pipelined with raw
// lgkm-only barriers. Cross-step LDS hazard guarded by the poll itself
// (WG-mates are same-class producers).
__global__ __launch_bounds__(256, 1)
void rnn_kernel(const int* __restrict__ xT,
                const float* __restrict__ tableF, const float* __restrict__ tableB,
                const short* __restrict__ whhpack,
                unsigned long long* __restrict__ hsfF,
                unsigned long long* __restrict__ hsfB)
{
  extern __shared__ char lds[];   // 32 KB: ldsH [kt][q][lane] u64 (decoded h)
  char* ldsH = lds;
  const int tid = threadIdx.x;
  const int wg = blockIdx.x;
  const int dir = wg >> 5;
  const int bt = (wg >> 3) & 3;
  const int csh = wg & 7;
  const int lane = tid & 63;
  const int ct = tid >> 6;
  const int tt0 = csh * 8 + ct * 2;                    // my two 16-col tiles
  const int row = bt * 16 + (lane & 15);               // my batch row
  const int c4a = tt0 * 16 + (lane >> 4) * 4;          // tile0: 4 output cols
  const int c4b = c4a + 16;                            // tile1
  const float* table = dir ? tableB : tableF;
  unsigned long long* hsx = dir ? hsfB : hsfF;
  const int pub_a = bt * 4096 + (c4a >> 5) * 128 + ((c4a >> 2) & 1) * 64 +
                    (lane & 15) + ((c4a >> 3) & 3) * 16;
  const int pub_b = pub_a + 32;                        // derived: c4b = c4a+16
  const i32x4* wsrc = (const i32x4*)whhpack;
  const size_t wbase0 = (size_t)(dir * 64 + tt0) * 2048 + lane;
  const size_t wbase1 = wbase0 + 2048;

  const f32x4 zv = {0.f, 0.f, 0.f, 0.f};

#define ENC(h) ({ union { _Float16 f; unsigned short u; } cv_; cv_.f = (_Float16)(h); \
                  unsigned short u_ = (cv_.u == 0x8000u) ? 0u : cv_.u; \
                  (unsigned long long)(u_ ^ 0x8000u); })

  // ---- prologue: step 0 (h_0 = tanh(xw)) ----
  {
    int t0 = dir ? 511 : 0;
    int v = xT[t0 * 64 + row];
    f32x4 xwa = *(const f32x4*)(table + v * 1024 + c4a);
    f32x4 xwb = *(const f32x4*)(table + v * 1024 + c4b);
    unsigned long long hxa = 0, hxb = 0;
    #pragma unroll
    for (int r = 0; r < 4; ++r) {
      hxa |= ENC(fast_tanh(xwa[r])) << (16 * r);
      hxb |= ENC(fast_tanh(xwb[r])) << (16 * r);
    }
    __hip_atomic_store(hsx + (size_t)t0 * 16384 + pub_a, hxa,
                       __ATOMIC_RELAXED, __HIP_MEMORY_SCOPE_AGENT);
    __hip_atomic_store(hsx + (size_t)t0 * 16384 + pub_b, hxb,
                       __ATOMIC_RELAXED, __HIP_MEMORY_SCOPE_AGENT);
  }

#define LDX(p) __hip_atomic_load((p), __ATOMIC_RELAXED, __HIP_MEMORY_SCOPE_AGENT)

  for (int s = 1; s < 512; ++s) {
    const int t = dir ? (511 - s) : s;
    const int tprev = dir ? (t + 1) : (t - 1);
    // xw gather early (independent; hides under poll)
    int v = xT[t * 64 + row];
    f32x4 xwa = *(const f32x4*)(table + v * 1024 + c4a);
    f32x4 xwb = *(const f32x4*)(table + v * 1024 + c4b);

    // my 16 staged words of h_{s-1}; batch0 = jj 0..3 (kt 0..15),
    // batch1 = jj 4..7 (kt 16..31). Issue BOTH before polling batch0.
    const unsigned long long* sp =
        hsx + (size_t)tprev * 16384 + bt * 4096 + tid * 2;
    unsigned long long a0[4], b0[4], a1[4], b1[4];
    #pragma unroll
    for (int i = 0; i < 4; ++i) {
      a0[i] = LDX(sp + i * 512);
      b0[i] = LDX(sp + i * 512 + 1);
    }
    #pragma unroll
    for (int i = 0; i < 4; ++i) {
      a1[i] = LDX(sp + (4 + i) * 512);
      b1[i] = LDX(sp + (4 + i) * 512 + 1);
    }

    // poll batch0 (nonzero == written)
    for (;;) {
      int miss = 0;
      #pragma unroll
      for (int i = 0; i < 4; ++i)
        miss |= (a0[i] == 0ULL) | (b0[i] == 0ULL);
      if (!__ballot(miss)) break;
      __builtin_amdgcn_s_sleep(1);
      #pragma unroll
      for (int i = 0; i < 4; ++i) {
        a0[i] = LDX(sp + i * 512);
        b0[i] = LDX(sp + i * 512 + 1);
      }
    }
    // stage batch0 (decode) -> ldsH kt 0..15
    #pragma unroll
    for (int jj = 0; jj < 4; ++jj) {
      u64x2 w; w[0] = a0[jj] ^ FLIP64; w[1] = b0[jj] ^ FLIP64;
      *(u64x2*)(ldsH + jj * 4096 + tid * 16) = w;
    }
    // raw barrier: drain LDS writes only — batch1 loads stay in flight
    asm volatile("s_waitcnt lgkmcnt(0)" ::: "memory");
    __builtin_amdgcn_s_barrier();
    asm volatile("" ::: "memory");

    f32x4 accA[4] = {zv, zv, zv, zv};
    f32x4 accB[4] = {zv, zv, zv, zv};
    #pragma unroll
    for (int kt = 0; kt < 16; ++kt) {   // hides batch1's L3 RTT
      u64x2 bv;
      bv[0] = *(const unsigned long long*)(ldsH + (kt * 128 + lane) * 8);
      bv[1] = *(const unsigned long long*)(ldsH + (kt * 128 + 64 + lane) * 8);
      f16x8 bf = __builtin_bit_cast(f16x8, bv);
      f16x8 af0 = __builtin_bit_cast(f16x8, wsrc[wbase0 + (size_t)kt * 64]);
      f16x8 af1 = __builtin_bit_cast(f16x8, wsrc[wbase1 + (size_t)kt * 64]);
      accA[kt & 3] =
          __builtin_amdgcn_mfma_f32_16x16x32_f16(af0, bf, accA[kt & 3], 0, 0, 0);
      accB[kt & 3] =
          __builtin_amdgcn_mfma_f32_16x16x32_f16(af1, bf, accB[kt & 3], 0, 0, 0);
    }

    // poll batch1 (usually already nonzero)
    for (;;) {
      int miss = 0;
      #pragma unroll
      for (int i = 0; i < 4; ++i)
        miss |= (a1[i] == 0ULL) | (b1[i] == 0ULL);
      if (!__ballot(miss)) break;
      __builtin_amdgcn_s_sleep(1);
      #pragma unroll
      for (int i = 0; i < 4; ++i) {
        a1[i] = LDX(sp + (4 + i) * 512);
        b1[i] = LDX(sp + (4 + i) * 512 + 1);
      }
    }
    // stage batch1 -> ldsH kt 16..31
    #pragma unroll
    for (int jj = 0; jj < 4; ++jj) {
      u64x2 w; w[0] = a1[jj] ^ FLIP64; w[1] = b1[jj] ^ FLIP64;
      *(u64x2*)(ldsH + (4 + jj) * 4096 + tid * 16) = w;
    }
    asm volatile("s_waitcnt lgkmcnt(0)" ::: "memory");
    __builtin_amdgcn_s_barrier();
    asm volatile("" ::: "memory");

    #pragma unroll
    for (int kt = 16; kt < 32; ++kt) {
      u64x2 bv;
      bv[0] = *(const unsigned long long*)(ldsH + (kt * 128 + lane) * 8);
      bv[1] = *(const unsigned long long*)(ldsH + (kt * 128 + 64 + lane) * 8);
      f16x8 bf = __builtin_bit_cast(f16x8, bv);
      f16x8 af0 = __builtin_bit_cast(f16x8, wsrc[wbase0 + (size_t)kt * 64]);
      f16x8 af1 = __builtin_bit_cast(f16x8, wsrc[wbase1 + (size_t)kt * 64]);
      accA[kt & 3] =
          __builtin_amdgcn_mfma_f32_16x16x32_f16(af0, bf, accA[kt & 3], 0, 0, 0);
      accB[kt & 3] =
          __builtin_amdgcn_mfma_f32_16x16x32_f16(af1, bf, accB[kt & 3], 0, 0, 0);
    }

    // epilogue: tanh, encode, two fire-and-forget publishes
    f32x4 accsA = (accA[0] + accA[1]) + (accA[2] + accA[3]);
    f32x4 accsB = (accB[0] + accB[1]) + (accB[2] + accB[3]);
    unsigned long long hxa = 0, hxb = 0;
    #pragma unroll
    for (int r = 0; r < 4; ++r) {
      hxa |= ENC(fast_tanh(accsA[r] + xwa[r])) << (16 * r);
      hxb |= ENC(fast_tanh(accsB[r] + xwb[r])) << (16 * r);
    }
    __hip_atomic_store(hsx + (size_t)t * 16384 + pub_a, hxa,
                       __ATOMIC_RELAXED, __HIP_MEMORY_SCOPE_AGENT);
    __hip_atomic_store(hsx + (size_t)t * 16384 + pub_b, hxb,
                       __ATOMIC_RELAXED, __HIP_MEMORY_SCOPE_AGENT);
  }
#undef LDX
#undef ENC
}

// ---------------- FC: out[b*512+t][1024] = concat(hf,hb)@Wfc^T + b (fp16 frag) ----
// Block = (4 consecutive t, ob); wave w owns t = 4*bx + w (64 rows x 64 cols).
__global__ __launch_bounds__(256, 2)
void fc_kernel(const unsigned long long* __restrict__ hsfF,
               const unsigned long long* __restrict__ hsfB,
               const short* __restrict__ wfcpack, const float* __restrict__ bfc,
               float* __restrict__ out)
{
  __shared__ unsigned long long Alds[4096];  // 32 KB [w4][btl*2+rr][128]
  __shared__ short Blds[4096];               // 8 KB fp16 fragment-linear
  const int tid = threadIdx.x;
  const int lane = tid & 63;
  const int w = tid >> 6;            // wave = t-local
  const int t = blockIdx.x * 4 + w;
  const int ob = blockIdx.y;
  const int btl = lane >> 4;         // bt block staged by this lane
  const int li = lane & 15;

  const i32x4 flip32 = {(int)0x80008000, (int)0x80008000,
                        (int)0x80008000, (int)0x80008000};
  f32x4 z = {0.f, 0.f, 0.f, 0.f};
  f32x4 acc[4][4] = {{z, z, z, z}, {z, z, z, z}, {z, z, z, z}, {z, z, z, z}};
  unsigned long long* Aw = &Alds[w * 1024];

  for (int kc = 0; kc < 32; ++kc) {
    {  // A-stage: each wave stages its own t (1024 u64 = 8 KB), 16 u64/lane
      const unsigned long long* src =
          (kc < 16 ? hsfF : hsfB) + (size_t)t * 16384;
      int kt0 = (kc & 15) * 2;
      const unsigned long long* ap = src + btl * 4096 + kt0 * 128 + li * 8;
      #pragma unroll
      for (int rr = 0; rr < 2; ++rr) {
        i32x4 q0 = *(const i32x4*)(ap + rr * 128) ^ flip32;
        i32x4 q1 = *(const i32x4*)(ap + rr * 128 + 2) ^ flip32;
        i32x4 q2 = *(const i32x4*)(ap + rr * 128 + 4) ^ flip32;
        i32x4 q3 = *(const i32x4*)(ap + rr * 128 + 6) ^ flip32;
        unsigned long long* dst = &Aw[(btl * 2 + rr) * 128 + li * 8];
        *(i32x4*)(dst) = q0;
        *(i32x4*)(dst + 2) = q1;
        *(i32x4*)(dst + 4) = q2;
        *(i32x4*)(dst + 6) = q3;
      }
    }
    {  // B-stage: fragment-linear contiguous copy (2 x k32 blocks)
      const i32x4* src = (const i32x4*)(wfcpack + ((size_t)ob * 64 + kc * 2) * 2048);
      i32x4* dst = (i32x4*)Blds;
      dst[tid] = src[tid];
      dst[tid + 256] = src[tid + 256];
    }
    __syncthreads();
    #pragma unroll
    for (int k2 = 0; k2 < 2; ++k2) {
      f16x8 afr[4];
      #pragma unroll
      for (int mi = 0; mi < 4; ++mi) {
        u64x2 av;
        av[0] = Aw[(mi * 2 + k2) * 128 + lane];
        av[1] = Aw[(mi * 2 + k2) * 128 + 64 + lane];
        afr[mi] = __builtin_bit_cast(f16x8, av);
      }
      #pragma unroll
      for (int ni = 0; ni < 4; ++ni) {
        f16x8 bfr = *(const f16x8*)((const char*)Blds + ((k2 * 4 + ni) * 64 + lane) * 16);
        #pragma unroll
        for (int mi = 0; mi < 4; ++mi)
          acc[mi][ni] = __builtin_amdgcn_mfma_f32_16x16x32_f16(afr[mi], bfr, acc[mi][ni], 0, 0, 0);
      }
    }
    __syncthreads();
  }
  #pragma unroll
  for (int mi = 0; mi < 4; ++mi) {
    #pragma unroll
    for (int ni = 0; ni < 4; ++ni) {
      int o = ob * 64 + ni * 16 + (lane & 15);
      float bias = bfc[o];
      #pragma unroll
      for (int r = 0; r < 4; ++r) {
        int b = mi * 16 + (lane >> 4) * 4 + r;
        out[(size_t)(b * 512 + t) * O_ + o] = acc[mi][ni][r] + bias;
      }
    }
  }
}

extern "C" void kernel_launch(void* const* d_in, const int* in_sizes, int n_in,
                              void* d_out, int out_size, void* d_ws, size_t ws_size,
                              hipStream_t stream) {
  const int* x = (const int*)d_in[0];
  const float* WihF = (const float*)d_in[1];
  const float* WhhF = (const float*)d_in[2];
  const float* bihF = (const float*)d_in[3];
  const float* bhhF = (const float*)d_in[4];
  const float* WihB = (const float*)d_in[5];
  const float* WhhB = (const float*)d_in[6];
  const float* bihB = (const float*)d_in[7];
  const float* bhhB = (const float*)d_in[8];
  const float* Wfc  = (const float*)d_in[9];
  const float* bfc  = (const float*)d_in[10];
  float* out = (float*)d_out;
  char* ws = (char*)d_ws;

  float* tableF = (float*)(ws + OFF_TABLE_F);
  float* tableB = (float*)(ws + OFF_TABLE_B);
  int* xT = (int*)(ws + OFF_XT);
  short* whhpack = (short*)(ws + OFF_WHH);
  short* wfcpack = (short*)(ws + OFF_WFC);
  unsigned long long* hsfF = (unsigned long long*)(ws + OFF_HSF);
  unsigned long long* hsfB = (unsigned long long*)(ws + OFF_HSB);

  hipFuncSetAttribute((const void*)rnn_kernel,
                      hipFuncAttributeMaxDynamicSharedMemorySize, 32768);

  prep_kernel<<<dim3(2048), dim3(256), 0, stream>>>(
      x, WihF, WhhF, bihF, bhhF, WihB, WhhB, bihB, bhhB, Wfc,
      tableF, tableB, xT, whhpack, wfcpack, hsfF);
  rnn_kernel<<<dim3(64), dim3(256), 32768, stream>>>(
      xT, tableF, tableB, whhpack, hsfF, hsfB);
  fc_kernel<<<dim3(128, 16), dim3(256), 0, stream>>>(
      hsfF, hsfB, wfcpack, bfc, out);
}

// Round 14
// 2134.156 us; speedup vs baseline: 1.1058x; 1.1058x over previous
//
#include <hip/hip_runtime.h>
#include <math.h>

#define B_ 64
#define T_ 512
#define H_ 1024
#define V_ 256
#define O_ 1024
#define KFC 2048

typedef short bf16x8 __attribute__((ext_vector_type(8)));
typedef _Float16 f16x8 __attribute__((ext_vector_type(8)));
typedef float f32x4 __attribute__((ext_vector_type(4)));
typedef int   i32x4 __attribute__((ext_vector_type(4)));
typedef unsigned long long u64x2 __attribute__((ext_vector_type(2)));

#define FLIP64 0x8000800080008000ULL

// ---- workspace layout (bytes) ----
#define OFF_TABLE_F 0                 // [V][H] f32 (W_ih^T + b_ih + b_hh), fwd
#define OFF_TABLE_B 1048576           // same, bwd
#define OFF_XT      2097152           // [T][B] i32 (transposed x)
#define OFF_WHH     2228224           // fp16 [d][cs16][ct4][kt32][lane64][8] (4 MB)
#define OFF_WFC     6422528           // fp16 [ob][k32][nt][lane][8] (4 MB)
#define OFF_HSF     10616832          // fp16 frag, sign-flipped: [t][bt][kt][q][lane'] u64 (64 MB)
#define OFF_HSB     77725696          // same, bwd (64 MB)  — adjacent to HSF

__device__ __forceinline__ float fast_tanh(float zz) {
  float e = __expf(2.0f * zz);
  return 1.0f - 2.0f * __builtin_amdgcn_rcpf(e + 1.0f);
}

// ---------------- prep: tables, transposes, packed weights, hs zeroing ----------------
__global__ void prep_kernel(const int* __restrict__ x,
    const float* __restrict__ WihF, const float* __restrict__ WhhF,
    const float* __restrict__ bihF, const float* __restrict__ bhhF,
    const float* __restrict__ WihB, const float* __restrict__ WhhB,
    const float* __restrict__ bihB, const float* __restrict__ bhhB,
    const float* __restrict__ Wfc,
    float* __restrict__ tableF, float* __restrict__ tableB,
    int* __restrict__ xT, short* __restrict__ whhpack,
    short* __restrict__ wfcpack, unsigned long long* __restrict__ hsz)
{
  const long NT1 = 524288, NT2 = 32768, NT3 = 2097152, NT4 = 2097152;
  const long NT5 = 16777216;  // zero hsF+hsB (adjacent, 128 MB) as u64
  const long total = NT1 + NT2 + NT3 + NT4 + NT5;
  for (long i = (long)blockIdx.x * blockDim.x + threadIdx.x; i < total;
       i += (long)gridDim.x * blockDim.x) {
    long j = i;
    if (j < NT1) {
      int d = (int)(j >> 18);
      int r = (int)(j & 262143);
      int v = r >> 10, h = r & 1023;
      const float* Wih = d ? WihB : WihF;
      const float* bi  = d ? bihB : bihF;
      const float* bh  = d ? bhhB : bhhF;
      (d ? tableB : tableF)[r] = Wih[h * V_ + v] + bi[h] + bh[h];
      continue;
    }
    j -= NT1;
    if (j < NT2) {
      int t = (int)(j >> 6), bb = (int)(j & 63);
      xT[j] = x[bb * T_ + t];
      continue;
    }
    j -= NT2;
    if (j < NT3) {
      // whhpack [d][cs16][ct4][kt32][lane64][8]:
      //   c = cs*64 + ct*16 + (lane&15), k = kt*32 + (lane>>4)*8 + jj
      int d = (int)(j >> 20);
      int r = (int)(j & 1048575);
      int jj = r & 7;
      int lanei = (r >> 3) & 63;
      int kt = (r >> 9) & 31;
      int cti = (r >> 14) & 3;
      int csi = (r >> 16) & 15;
      int c = csi * 64 + cti * 16 + (lanei & 15);
      int k = kt * 32 + (lanei >> 4) * 8 + jj;
      float w = (d ? WhhB : WhhF)[c * H_ + k];
      _Float16 wh = (_Float16)w;
      whhpack[j] = __builtin_bit_cast(short, wh);
      continue;
    }
    j -= NT3;
    if (j < NT4) {
      int jj = (int)(j & 7);
      int lanei = (int)((j >> 3) & 63);
      int nti = (int)((j >> 9) & 3);
      int k32 = (int)((j >> 11) & 63);
      int obi = (int)(j >> 17);
      int o = obi * 64 + nti * 16 + (lanei & 15);
      int k = k32 * 32 + (lanei >> 4) * 8 + jj;
      _Float16 wf = (_Float16)Wfc[(long)o * KFC + k];
      wfcpack[j] = __builtin_bit_cast(short, wf);
      continue;
    }
    j -= NT4;
    hsz[j] = 0ULL;  // unwritten sentinel for the self-signaling exchange
    continue;
  }
}

// ---------------- fused: persistent recurrence (WG 0-127) + FC (WG 128-255) ---------
// rnn part: R12 verbatim (best: 1306 us). FC part: self-gating on the same
// self-signaling sentinels, center-out t-block schedule so each pass becomes
// available just before it's processed; FC rides the rnn's idle half-machine.
__global__ __launch_bounds__(256, 1)
void fused_kernel(const int* __restrict__ xT,
                  const float* __restrict__ tableF, const float* __restrict__ tableB,
                  const short* __restrict__ whhpack,
                  const short* __restrict__ wfcpack, const float* __restrict__ bfc,
                  unsigned long long* __restrict__ hsfF,
                  unsigned long long* __restrict__ hsfB,
                  float* __restrict__ out)
{
  extern __shared__ char lds[];
  const int tid = threadIdx.x;
  const int lane = tid & 63;
  const f32x4 zv = {0.f, 0.f, 0.f, 0.f};

#define LDX(p) __hip_atomic_load((p), __ATOMIC_RELAXED, __HIP_MEMORY_SCOPE_AGENT)

  if (blockIdx.x < 128) {
    // ================= RNN (R12 verbatim) =================
    char* ldsH = lds;               // 32 KB [kt][q][lane] u64 (decoded h)
    const int wg = blockIdx.x;
    const int dir = wg >> 6;
    const int bt = (wg >> 4) & 3;
    const int cs = wg & 15;
    const int ct = tid >> 6;
    const int row = bt * 16 + (lane & 15);
    const int c4 = cs * 64 + ct * 16 + (lane >> 4) * 4;
    const float* table = dir ? tableB : tableF;
    unsigned long long* hsx = dir ? hsfB : hsfF;
    const int pub_off = bt * 4096 + (c4 >> 5) * 128 + ((c4 >> 2) & 1) * 64 +
                        (lane & 15) + ((c4 >> 3) & 3) * 16;

    f16x8 Wreg[32];
    {
      const i32x4* wsrc = (const i32x4*)whhpack + (size_t)(dir * 16 + cs) * 8192;
      #pragma unroll
      for (int kt = 0; kt < 32; ++kt)
        Wreg[kt] = __builtin_bit_cast(f16x8, wsrc[(ct * 32 + kt) * 64 + lane]);
    }

    // prologue: step 0
    {
      int t0 = dir ? 511 : 0;
      int v = xT[t0 * 64 + row];
      f32x4 xwv = *(const f32x4*)(table + v * 1024 + c4);
      unsigned long long hx = 0;
      #pragma unroll
      for (int r = 0; r < 4; ++r) {
        float h = fast_tanh(xwv[r]);
        union { _Float16 f; unsigned short u; } cv; cv.f = (_Float16)h;
        unsigned short u = (cv.u == 0x8000u) ? 0u : cv.u;
        hx |= (unsigned long long)(u ^ 0x8000u) << (16 * r);
      }
      __hip_atomic_store(hsx + (size_t)t0 * 16384 + pub_off, hx,
                         __ATOMIC_RELAXED, __HIP_MEMORY_SCOPE_AGENT);
    }

    for (int s = 1; s < 512; ++s) {
      const int t = dir ? (511 - s) : s;
      const int tprev = dir ? (t + 1) : (t - 1);
      int v = xT[t * 64 + row];
      f32x4 xwv = *(const f32x4*)(table + v * 1024 + c4);

      const unsigned long long* sp =
          hsx + (size_t)tprev * 16384 + bt * 4096 + tid * 2;
      unsigned long long a0[4], b0[4], a1[4], b1[4];
      #pragma unroll
      for (int i = 0; i < 4; ++i) {
        a0[i] = LDX(sp + i * 512);
        b0[i] = LDX(sp + i * 512 + 1);
      }
      #pragma unroll
      for (int i = 0; i < 4; ++i) {
        a1[i] = LDX(sp + (4 + i) * 512);
        b1[i] = LDX(sp + (4 + i) * 512 + 1);
      }

      for (;;) {
        int miss = 0;
        #pragma unroll
        for (int i = 0; i < 4; ++i)
          miss |= (a0[i] == 0ULL) | (b0[i] == 0ULL);
        if (!__ballot(miss)) break;
        __builtin_amdgcn_s_sleep(1);
        #pragma unroll
        for (int i = 0; i < 4; ++i) {
          a0[i] = LDX(sp + i * 512);
          b0[i] = LDX(sp + i * 512 + 1);
        }
      }
      #pragma unroll
      for (int jj = 0; jj < 4; ++jj) {
        u64x2 w; w[0] = a0[jj] ^ FLIP64; w[1] = b0[jj] ^ FLIP64;
        *(u64x2*)(ldsH + jj * 4096 + tid * 16) = w;
      }
      asm volatile("s_waitcnt lgkmcnt(0)" ::: "memory");
      __builtin_amdgcn_s_barrier();
      asm volatile("" ::: "memory");

      f32x4 acc4[4] = {zv, zv, zv, zv};
      #pragma unroll
      for (int kt = 0; kt < 16; ++kt) {
        u64x2 bv;
        bv[0] = *(const unsigned long long*)(ldsH + (kt * 128 + lane) * 8);
        bv[1] = *(const unsigned long long*)(ldsH + (kt * 128 + 64 + lane) * 8);
        f16x8 bf = __builtin_bit_cast(f16x8, bv);
        acc4[kt & 3] =
            __builtin_amdgcn_mfma_f32_16x16x32_f16(Wreg[kt], bf, acc4[kt & 3], 0, 0, 0);
      }

      for (;;) {
        int miss = 0;
        #pragma unroll
        for (int i = 0; i < 4; ++i)
          miss |= (a1[i] == 0ULL) | (b1[i] == 0ULL);
        if (!__ballot(miss)) break;
        __builtin_amdgcn_s_sleep(1);
        #pragma unroll
        for (int i = 0; i < 4; ++i) {
          a1[i] = LDX(sp + (4 + i) * 512);
          b1[i] = LDX(sp + (4 + i) * 512 + 1);
        }
      }
      #pragma unroll
      for (int jj = 0; jj < 4; ++jj) {
        u64x2 w; w[0] = a1[jj] ^ FLIP64; w[1] = b1[jj] ^ FLIP64;
        *(u64x2*)(ldsH + (4 + jj) * 4096 + tid * 16) = w;
      }
      asm volatile("s_waitcnt lgkmcnt(0)" ::: "memory");
      __builtin_amdgcn_s_barrier();
      asm volatile("" ::: "memory");

      #pragma unroll
      for (int kt = 16; kt < 32; ++kt) {
        u64x2 bv;
        bv[0] = *(const unsigned long long*)(ldsH + (kt * 128 + lane) * 8);
        bv[1] = *(const unsigned long long*)(ldsH + (kt * 128 + 64 + lane) * 8);
        f16x8 bf = __builtin_bit_cast(f16x8, bv);
        acc4[kt & 3] =
            __builtin_amdgcn_mfma_f32_16x16x32_f16(Wreg[kt], bf, acc4[kt & 3], 0, 0, 0);
      }

      f32x4 accs = (acc4[0] + acc4[1]) + (acc4[2] + acc4[3]);
      unsigned long long hx = 0;
      #pragma unroll
      for (int r = 0; r < 4; ++r) {
        float h = fast_tanh(accs[r] + xwv[r]);
        union { _Float16 f; unsigned short u; } cv; cv.f = (_Float16)h;
        unsigned short u = (cv.u == 0x8000u) ? 0u : cv.u;
        hx |= (unsigned long long)(u ^ 0x8000u) << (16 * r);
      }
      __hip_atomic_store(hsx + (size_t)t * 16384 + pub_off, hx,
                         __ATOMIC_RELAXED, __HIP_MEMORY_SCOPE_AGENT);
    }
  } else {
    // ================= FC (self-gating, center-out schedule) =================
    unsigned long long* Alds = (unsigned long long*)lds;     // 32 KB
    short* Blds = (short*)(lds + 32768);                     // 8 KB
    const int f = blockIdx.x - 128;   // 0..127
    const int ob = f >> 3;            // 0..15
    const int g8 = f & 7;
    const int w = tid >> 6;           // wave = t-local within block of 4 t
    const int btl = lane >> 4;
    const int li = lane & 15;
    unsigned long long* Aw = &Alds[w * 1024];

    for (int p = 0; p < 16; ++p) {
      int i = p * 8 + g8;
      int tb = (i & 1) ? (64 + (i >> 1)) : (63 - (i >> 1));
      int t = tb * 4 + w;

      // coarse availability gate: sample 64 words from each dir's t-block
      {
        const unsigned long long* sF = hsfF + (size_t)t * 16384 + lane * 256;
        const unsigned long long* sB = hsfB + (size_t)t * 16384 + lane * 256;
        while (__ballot((LDX(sF) == 0ULL) | (LDX(sB) == 0ULL)))
          __builtin_amdgcn_s_sleep(32);
      }

      f32x4 acc[4][4] = {{zv, zv, zv, zv}, {zv, zv, zv, zv},
                         {zv, zv, zv, zv}, {zv, zv, zv, zv}};

      for (int kc = 0; kc < 32; ++kc) {
        {  // A-stage with verify: 16 u64/lane, sc1 loads (fresh), poll zeros
          const unsigned long long* src =
              (kc < 16 ? hsfF : hsfB) + (size_t)t * 16384;
          int kt0 = (kc & 15) * 2;
          const unsigned long long* ap = src + btl * 4096 + kt0 * 128 + li * 8;
          unsigned long long vv[16];
          #pragma unroll
          for (int rr = 0; rr < 2; ++rr)
            #pragma unroll
            for (int n = 0; n < 8; ++n)
              vv[rr * 8 + n] = LDX(ap + rr * 128 + n);
          for (;;) {
            int miss = 0;
            #pragma unroll
            for (int q = 0; q < 16; ++q) miss |= (vv[q] == 0ULL);
            if (!__ballot(miss)) break;
            __builtin_amdgcn_s_sleep(2);
            #pragma unroll
            for (int rr = 0; rr < 2; ++rr)
              #pragma unroll
              for (int n = 0; n < 8; ++n)
                vv[rr * 8 + n] = LDX(ap + rr * 128 + n);
          }
          #pragma unroll
          for (int rr = 0; rr < 2; ++rr)
            #pragma unroll
            for (int n = 0; n < 8; ++n)
              Aw[(btl * 2 + rr) * 128 + li * 8 + n] = vv[rr * 8 + n] ^ FLIP64;
        }
        {  // B-stage: fragment-linear contiguous copy
          const i32x4* src = (const i32x4*)(wfcpack + ((size_t)ob * 64 + kc * 2) * 2048);
          i32x4* dst = (i32x4*)Blds;
          dst[tid] = src[tid];
          dst[tid + 256] = src[tid + 256];
        }
        __syncthreads();
        #pragma unroll
        for (int k2 = 0; k2 < 2; ++k2) {
          f16x8 afr[4];
          #pragma unroll
          for (int mi = 0; mi < 4; ++mi) {
            u64x2 av;
            av[0] = Aw[(mi * 2 + k2) * 128 + lane];
            av[1] = Aw[(mi * 2 + k2) * 128 + 64 + lane];
            afr[mi] = __builtin_bit_cast(f16x8, av);
          }
          #pragma unroll
          for (int ni = 0; ni < 4; ++ni) {
            f16x8 bfr = *(const f16x8*)((const char*)Blds + ((k2 * 4 + ni) * 64 + lane) * 16);
            #pragma unroll
            for (int mi = 0; mi < 4; ++mi)
              acc[mi][ni] = __builtin_amdgcn_mfma_f32_16x16x32_f16(afr[mi], bfr, acc[mi][ni], 0, 0, 0);
          }
        }
        __syncthreads();
      }
      #pragma unroll
      for (int mi = 0; mi < 4; ++mi) {
        #pragma unroll
        for (int ni = 0; ni < 4; ++ni) {
          int o = ob * 64 + ni * 16 + (lane & 15);
          float bias = bfc[o];
          #pragma unroll
          for (int r = 0; r < 4; ++r) {
            int b = mi * 16 + (lane >> 4) * 4 + r;
            out[(size_t)(b * 512 + t) * O_ + o] = acc[mi][ni][r] + bias;
          }
        }
      }
    }
  }
#undef LDX
}

extern "C" void kernel_launch(void* const* d_in, const int* in_sizes, int n_in,
                              void* d_out, int out_size, void* d_ws, size_t ws_size,
                              hipStream_t stream) {
  const int* x = (const int*)d_in[0];
  const float* WihF = (const float*)d_in[1];
  const float* WhhF = (const float*)d_in[2];
  const float* bihF = (const float*)d_in[3];
  const float* bhhF = (const float*)d_in[4];
  const float* WihB = (const float*)d_in[5];
  const float* WhhB = (const float*)d_in[6];
  const float* bihB = (const float*)d_in[7];
  const float* bhhB = (const float*)d_in[8];
  const float* Wfc  = (const float*)d_in[9];
  const float* bfc  = (const float*)d_in[10];
  float* out = (float*)d_out;
  char* ws = (char*)d_ws;

  float* tableF = (float*)(ws + OFF_TABLE_F);
  float* tableB = (float*)(ws + OFF_TABLE_B);
  int* xT = (int*)(ws + OFF_XT);
  short* whhpack = (short*)(ws + OFF_WHH);
  short* wfcpack = (short*)(ws + OFF_WFC);
  unsigned long long* hsfF = (unsigned long long*)(ws + OFF_HSF);
  unsigned long long* hsfB = (unsigned long long*)(ws + OFF_HSB);

  hipFuncSetAttribute((const void*)fused_kernel,
                      hipFuncAttributeMaxDynamicSharedMemorySize, 40960);

  prep_kernel<<<dim3(2048), dim3(256), 0, stream>>>(
      x, WihF, WhhF, bihF, bhhF, WihB, WhhB, bihB, bhhB, Wfc,
      tableF, tableB, xT, whhpack, wfcpack, hsfF);
  fused_kernel<<<dim3(256), dim3(256), 40960, stream>>>(
      xT, tableF, tableB, whhpack, wfcpack, bfc, hsfF, hsfB, out);
}

// Round 16
// 1477.057 us; speedup vs baseline: 1.5978x; 1.4449x over previous
//
#include <hip/hip_runtime.h>
#include <math.h>

#define B_ 64
#define T_ 512
#define H_ 1024
#define V_ 256
#define O_ 1024
#define KFC 2048

typedef short bf16x8 __attribute__((ext_vector_type(8)));
typedef _Float16 f16x8 __attribute__((ext_vector_type(8)));
typedef float f32x4 __attribute__((ext_vector_type(4)));
typedef int   i32x4 __attribute__((ext_vector_type(4)));
typedef unsigned long long u64x2 __attribute__((ext_vector_type(2)));

#define FLIP64 0x8000800080008000ULL

// ---- workspace layout (bytes) ----
#define OFF_TABLE_F 0                 // [V][H] f32 (W_ih^T + b_ih + b_hh), fwd
#define OFF_TABLE_B 1048576           // same, bwd
#define OFF_XT      2097152           // [T][B] i32 (transposed x)
#define OFF_WHH     2228224           // fp16 [d][cs16][ct4][kt32][lane64][8] (4 MB)
#define OFF_WFC     6422528           // fp16 [ob][k32][nt][lane][8] (4 MB)
#define OFF_HSF     10616832          // fp16 frag, sign-flipped: [t][bt][kt][q][lane'] u64 (64 MB)
#define OFF_HSB     77725696          // same, bwd (64 MB)  — adjacent to HSF

__device__ __forceinline__ float fast_tanh(float zz) {
  float e = __expf(2.0f * zz);
  return 1.0f - 2.0f * __builtin_amdgcn_rcpf(e + 1.0f);
}

// ---------------- prep: tables, transposes, packed weights, hs zeroing ----------------
__global__ void prep_kernel(const int* __restrict__ x,
    const float* __restrict__ WihF, const float* __restrict__ WhhF,
    const float* __restrict__ bihF, const float* __restrict__ bhhF,
    const float* __restrict__ WihB, const float* __restrict__ WhhB,
    const float* __restrict__ bihB, const float* __restrict__ bhhB,
    const float* __restrict__ Wfc,
    float* __restrict__ tableF, float* __restrict__ tableB,
    int* __restrict__ xT, short* __restrict__ whhpack,
    short* __restrict__ wfcpack, unsigned long long* __restrict__ hsz)
{
  const long NT1 = 524288, NT2 = 32768, NT3 = 2097152, NT4 = 2097152;
  const long NT5 = 8388608;  // zero hsF+hsB (adjacent, 128 MB) as u64x2 (16B)
  const long total = NT1 + NT2 + NT3 + NT4 + NT5;
  for (long i = (long)blockIdx.x * blockDim.x + threadIdx.x; i < total;
       i += (long)gridDim.x * blockDim.x) {
    long j = i;
    if (j < NT1) {
      int d = (int)(j >> 18);
      int r = (int)(j & 262143);
      int v = r >> 10, h = r & 1023;
      const float* Wih = d ? WihB : WihF;
      const float* bi  = d ? bihB : bihF;
      const float* bh  = d ? bhhB : bhhF;
      (d ? tableB : tableF)[r] = Wih[h * V_ + v] + bi[h] + bh[h];
      continue;
    }
    j -= NT1;
    if (j < NT2) {
      int t = (int)(j >> 6), bb = (int)(j & 63);
      xT[j] = x[bb * T_ + t];
      continue;
    }
    j -= NT2;
    if (j < NT3) {
      // whhpack [d][cs16][ct4][kt32][lane64][8]:
      //   c = cs*64 + ct*16 + (lane&15), k = kt*32 + (lane>>4)*8 + jj
      int d = (int)(j >> 20);
      int r = (int)(j & 1048575);
      int jj = r & 7;
      int lanei = (r >> 3) & 63;
      int kt = (r >> 9) & 31;
      int cti = (r >> 14) & 3;
      int csi = (r >> 16) & 15;
      int c = csi * 64 + cti * 16 + (lanei & 15);
      int k = kt * 32 + (lanei >> 4) * 8 + jj;
      float w = (d ? WhhB : WhhF)[c * H_ + k];
      _Float16 wh = (_Float16)w;
      whhpack[j] = __builtin_bit_cast(short, wh);
      continue;
    }
    j -= NT3;
    if (j < NT4) {
      int jj = (int)(j & 7);
      int lanei = (int)((j >> 3) & 63);
      int nti = (int)((j >> 9) & 3);
      int k32 = (int)((j >> 11) & 63);
      int obi = (int)(j >> 17);
      int o = obi * 64 + nti * 16 + (lanei & 15);
      int k = k32 * 32 + (lanei >> 4) * 8 + jj;
      _Float16 wf = (_Float16)Wfc[(long)o * KFC + k];
      wfcpack[j] = __builtin_bit_cast(short, wf);
      continue;
    }
    j -= NT4;
    {  // unwritten sentinel for the self-signaling exchange
      u64x2 zz = {0ULL, 0ULL};
      *((u64x2*)hsz + j) = zz;
    }
    continue;
  }
}

// ---------------- persistent bidirectional recurrence (R12 verbatim) ----------------
__global__ __launch_bounds__(256, 1)
void rnn_kernel(const int* __restrict__ xT,
                const float* __restrict__ tableF, const float* __restrict__ tableB,
                const short* __restrict__ whhpack,
                unsigned long long* __restrict__ hsfF,
                unsigned long long* __restrict__ hsfB)
{
  extern __shared__ char lds[];   // 32 KB: ldsH [kt][q][lane] u64 (decoded h)
  char* ldsH = lds;
  const int tid = threadIdx.x;
  const int wg = blockIdx.x;
  const int dir = wg >> 6;
  const int bt = (wg >> 4) & 3;
  const int cs = wg & 15;
  const int lane = tid & 63;
  const int ct = tid >> 6;
  const int row = bt * 16 + (lane & 15);               // my batch row
  const int c4 = cs * 64 + ct * 16 + (lane >> 4) * 4;  // my 4 output cols
  const float* table = dir ? tableB : tableF;
  unsigned long long* hsx = dir ? hsfB : hsfF;
  const int pub_off = bt * 4096 + (c4 >> 5) * 128 + ((c4 >> 2) & 1) * 64 +
                      (lane & 15) + ((c4 >> 3) & 3) * 16;

  // one-time: W slice -> REGISTERS (fragment-linear, literal indices only)
  f16x8 Wreg[32];
  {
    const i32x4* wsrc = (const i32x4*)whhpack + (size_t)(dir * 16 + cs) * 8192;
    #pragma unroll
    for (int kt = 0; kt < 32; ++kt)
      Wreg[kt] = __builtin_bit_cast(f16x8, wsrc[(ct * 32 + kt) * 64 + lane]);
  }

  const f32x4 zv = {0.f, 0.f, 0.f, 0.f};

  // ---- prologue: step 0 (h_0 = tanh(xw)) ----
  {
    int t0 = dir ? 511 : 0;
    int v = xT[t0 * 64 + row];
    f32x4 xwv = *(const f32x4*)(table + v * 1024 + c4);
    unsigned long long hx = 0;
    #pragma unroll
    for (int r = 0; r < 4; ++r) {
      float h = fast_tanh(xwv[r]);
      union { _Float16 f; unsigned short u; } cv; cv.f = (_Float16)h;
      unsigned short u = (cv.u == 0x8000u) ? 0u : cv.u;  // -0 -> +0
      hx |= (unsigned long long)(u ^ 0x8000u) << (16 * r);  // field never 0
    }
    __hip_atomic_store(hsx + (size_t)t0 * 16384 + pub_off, hx,
                       __ATOMIC_RELAXED, __HIP_MEMORY_SCOPE_AGENT);
  }

#define LDX(p) __hip_atomic_load((p), __ATOMIC_RELAXED, __HIP_MEMORY_SCOPE_AGENT)

  for (int s = 1; s < 512; ++s) {
    const int t = dir ? (511 - s) : s;
    const int tprev = dir ? (t + 1) : (t - 1);
    // xw gather early (independent; hides under poll)
    int v = xT[t * 64 + row];
    f32x4 xwv = *(const f32x4*)(table + v * 1024 + c4);

    // my 16 staged words of h_{s-1}; batch0 = jj 0..3 (kt 0..15),
    // batch1 = jj 4..7 (kt 16..31). Issue BOTH before polling batch0.
    const unsigned long long* sp =
        hsx + (size_t)tprev * 16384 + bt * 4096 + tid * 2;
    unsigned long long a0[4], b0[4], a1[4], b1[4];
    #pragma unroll
    for (int i = 0; i < 4; ++i) {
      a0[i] = LDX(sp + i * 512);
      b0[i] = LDX(sp + i * 512 + 1);
    }
    #pragma unroll
    for (int i = 0; i < 4; ++i) {
      a1[i] = LDX(sp + (4 + i) * 512);
      b1[i] = LDX(sp + (4 + i) * 512 + 1);
    }

    // poll batch0 (nonzero == written)
    for (;;) {
      int miss = 0;
      #pragma unroll
      for (int i = 0; i < 4; ++i)
        miss |= (a0[i] == 0ULL) | (b0[i] == 0ULL);
      if (!__ballot(miss)) break;
      __builtin_amdgcn_s_sleep(1);
      #pragma unroll
      for (int i = 0; i < 4; ++i) {
        a0[i] = LDX(sp + i * 512);
        b0[i] = LDX(sp + i * 512 + 1);
      }
    }
    // stage batch0 (decode) -> ldsH kt 0..15
    #pragma unroll
    for (int jj = 0; jj < 4; ++jj) {
      u64x2 w; w[0] = a0[jj] ^ FLIP64; w[1] = b0[jj] ^ FLIP64;
      *(u64x2*)(ldsH + jj * 4096 + tid * 16) = w;
    }
    // raw barrier: drain LDS writes only — batch1 loads stay in flight
    asm volatile("s_waitcnt lgkmcnt(0)" ::: "memory");
    __builtin_amdgcn_s_barrier();
    asm volatile("" ::: "memory");

    f32x4 acc4[4] = {zv, zv, zv, zv};
    #pragma unroll
    for (int kt = 0; kt < 16; ++kt) {   // hides batch1's L3 RTT
      u64x2 bv;
      bv[0] = *(const unsigned long long*)(ldsH + (kt * 128 + lane) * 8);
      bv[1] = *(const unsigned long long*)(ldsH + (kt * 128 + 64 + lane) * 8);
      f16x8 bf = __builtin_bit_cast(f16x8, bv);
      acc4[kt & 3] =
          __builtin_amdgcn_mfma_f32_16x16x32_f16(Wreg[kt], bf, acc4[kt & 3], 0, 0, 0);
    }

    // poll batch1 (usually already nonzero)
    for (;;) {
      int miss = 0;
      #pragma unroll
      for (int i = 0; i < 4; ++i)
        miss |= (a1[i] == 0ULL) | (b1[i] == 0ULL);
      if (!__ballot(miss)) break;
      __builtin_amdgcn_s_sleep(1);
      #pragma unroll
      for (int i = 0; i < 4; ++i) {
        a1[i] = LDX(sp + (4 + i) * 512);
        b1[i] = LDX(sp + (4 + i) * 512 + 1);
      }
    }
    // stage batch1 -> ldsH kt 16..31
    #pragma unroll
    for (int jj = 0; jj < 4; ++jj) {
      u64x2 w; w[0] = a1[jj] ^ FLIP64; w[1] = b1[jj] ^ FLIP64;
      *(u64x2*)(ldsH + (4 + jj) * 4096 + tid * 16) = w;
    }
    asm volatile("s_waitcnt lgkmcnt(0)" ::: "memory");
    __builtin_amdgcn_s_barrier();
    asm volatile("" ::: "memory");

    #pragma unroll
    for (int kt = 16; kt < 32; ++kt) {
      u64x2 bv;
      bv[0] = *(const unsigned long long*)(ldsH + (kt * 128 + lane) * 8);
      bv[1] = *(const unsigned long long*)(ldsH + (kt * 128 + 64 + lane) * 8);
      f16x8 bf = __builtin_bit_cast(f16x8, bv);
      acc4[kt & 3] =
          __builtin_amdgcn_mfma_f32_16x16x32_f16(Wreg[kt], bf, acc4[kt & 3], 0, 0, 0);
    }

    // epilogue: tanh, encode, ONE fire-and-forget publish
    f32x4 accs = (acc4[0] + acc4[1]) + (acc4[2] + acc4[3]);
    unsigned long long hx = 0;
    #pragma unroll
    for (int r = 0; r < 4; ++r) {
      float h = fast_tanh(accs[r] + xwv[r]);
      union { _Float16 f; unsigned short u; } cv; cv.f = (_Float16)h;
      unsigned short u = (cv.u == 0x8000u) ? 0u : cv.u;
      hx |= (unsigned long long)(u ^ 0x8000u) << (16 * r);
    }
    __hip_atomic_store(hsx + (size_t)t * 16384 + pub_off, hx,
                       __ATOMIC_RELAXED, __HIP_MEMORY_SCOPE_AGENT);
  }
#undef LDX
}

// ---------------- FC: out[b*512+t][1024] = concat(hf,hb)@Wfc^T + b (fp16 frag) ----
// Block = (4 consecutive t, 2 ob); wave w owns t = 4*bx + w. A-tile staged once
// per kc feeds BOTH ob slices. LDS A-tile XOR-swizzled (16B-unit u' = u ^ row).
// FIX vs R15: B-stage copies the FULL 2 x 8 KB (1024 i32x4 units), 4 stores.
__global__ __launch_bounds__(256, 2)
void fc_kernel(const unsigned long long* __restrict__ hsfF,
               const unsigned long long* __restrict__ hsfB,
               const short* __restrict__ wfcpack, const float* __restrict__ bfc,
               float* __restrict__ out)
{
  __shared__ unsigned long long Alds[4096];  // 32 KB [w4][row8][col128 swz]
  __shared__ short Blds[8192];               // 16 KB: 2 ob slices
  const int tid = threadIdx.x;
  const int lane = tid & 63;
  const int w = tid >> 6;            // wave = t-local
  const int t = blockIdx.x * 4 + w;
  const int ob0 = blockIdx.y * 2;    // blockIdx.y in 0..7
  const int btl = lane >> 4;         // bt block staged by this lane
  const int li = lane & 15;

  const i32x4 flip32 = {(int)0x80008000, (int)0x80008000,
                        (int)0x80008000, (int)0x80008000};
  f32x4 z = {0.f, 0.f, 0.f, 0.f};
  f32x4 acc[2][4][4];
  #pragma unroll
  for (int ob = 0; ob < 2; ++ob)
    #pragma unroll
    for (int mi = 0; mi < 4; ++mi)
      #pragma unroll
      for (int ni = 0; ni < 4; ++ni)
        acc[ob][mi][ni] = z;
  unsigned long long* Aw = &Alds[w * 1024];

  for (int kc = 0; kc < 32; ++kc) {
    {  // A-stage: 16 u64/lane, i32x4 coalesced (64B/lane), swizzled store
      const unsigned long long* src =
          (kc < 16 ? hsfF : hsfB) + (size_t)t * 16384;
      int kt0 = (kc & 15) * 2;
      const unsigned long long* ap = src + btl * 4096 + kt0 * 128 + li * 8;
      #pragma unroll
      for (int rr = 0; rr < 2; ++rr) {
        int rowi = btl * 2 + rr;
        const i32x4* aq = (const i32x4*)(ap + rr * 128);
        #pragma unroll
        for (int k = 0; k < 4; ++k) {
          i32x4 q = aq[k] ^ flip32;
          *(i32x4*)&Aw[rowi * 128 + (((li * 4 + k) ^ rowi) << 1)] = q;
        }
      }
    }
    {  // B-stage: two fragment-linear slices (ob0, ob0+1), FULL 8 KB each
      const i32x4* s0 = (const i32x4*)(wfcpack + ((size_t)ob0 * 64 + kc * 2) * 2048);
      const i32x4* s1 = (const i32x4*)(wfcpack + ((size_t)(ob0 + 1) * 64 + kc * 2) * 2048);
      i32x4* dst = (i32x4*)Blds;
      dst[tid] = s0[tid];
      dst[tid + 256] = s0[tid + 256];
      dst[tid + 512] = s1[tid];
      dst[tid + 768] = s1[tid + 256];
    }
    __syncthreads();
    #pragma unroll
    for (int k2 = 0; k2 < 2; ++k2) {
      f16x8 afr[4];
      #pragma unroll
      for (int mi = 0; mi < 4; ++mi) {
        int rowi = mi * 2 + k2;
        int s0i = ((((lane >> 1) ^ rowi) << 1)) + (lane & 1);
        u64x2 av;
        av[0] = Aw[rowi * 128 + s0i];
        av[1] = Aw[rowi * 128 + 64 + s0i];
        afr[mi] = __builtin_bit_cast(f16x8, av);
      }
      #pragma unroll
      for (int ob = 0; ob < 2; ++ob) {
        #pragma unroll
        for (int ni = 0; ni < 4; ++ni) {
          f16x8 bfr = *(const f16x8*)((const char*)Blds + ob * 8192 +
                                      ((k2 * 4 + ni) * 64 + lane) * 16);
          #pragma unroll
          for (int mi = 0; mi < 4; ++mi)
            acc[ob][mi][ni] = __builtin_amdgcn_mfma_f32_16x16x32_f16(
                afr[mi], bfr, acc[ob][mi][ni], 0, 0, 0);
        }
      }
    }
    __syncthreads();
  }
  #pragma unroll
  for (int ob = 0; ob < 2; ++ob) {
    #pragma unroll
    for (int mi = 0; mi < 4; ++mi) {
      #pragma unroll
      for (int ni = 0; ni < 4; ++ni) {
        int o = (ob0 + ob) * 64 + ni * 16 + (lane & 15);
        float bias = bfc[o];
        #pragma unroll
        for (int r = 0; r < 4; ++r) {
          int b = mi * 16 + (lane >> 4) * 4 + r;
          out[(size_t)(b * 512 + t) * O_ + o] = acc[ob][mi][ni][r] + bias;
        }
      }
    }
  }
}

extern "C" void kernel_launch(void* const* d_in, const int* in_sizes, int n_in,
                              void* d_out, int out_size, void* d_ws, size_t ws_size,
                              hipStream_t stream) {
  const int* x = (const int*)d_in[0];
  const float* WihF = (const float*)d_in[1];
  const float* WhhF = (const float*)d_in[2];
  const float* bihF = (const float*)d_in[3];
  const float* bhhF = (const float*)d_in[4];
  const float* WihB = (const float*)d_in[5];
  const float* WhhB = (const float*)d_in[6];
  const float* bihB = (const float*)d_in[7];
  const float* bhhB = (const float*)d_in[8];
  const float* Wfc  = (const float*)d_in[9];
  const float* bfc  = (const float*)d_in[10];
  float* out = (float*)d_out;
  char* ws = (char*)d_ws;

  float* tableF = (float*)(ws + OFF_TABLE_F);
  float* tableB = (float*)(ws + OFF_TABLE_B);
  int* xT = (int*)(ws + OFF_XT);
  short* whhpack = (short*)(ws + OFF_WHH);
  short* wfcpack = (short*)(ws + OFF_WFC);
  unsigned long long* hsfF = (unsigned long long*)(ws + OFF_HSF);
  unsigned long long* hsfB = (unsigned long long*)(ws + OFF_HSB);

  hipFuncSetAttribute((const void*)rnn_kernel,
                      hipFuncAttributeMaxDynamicSharedMemorySize, 32768);

  prep_kernel<<<dim3(2048), dim3(256), 0, stream>>>(
      x, WihF, WhhF, bihF, bhhF, WihB, WhhB, bihB, bhhB, Wfc,
      tableF, tableB, xT, whhpack, wfcpack, hsfF);
  rnn_kernel<<<dim3(128), dim3(256), 32768, stream>>>(
      xT, tableF, tableB, whhpack, hsfF, hsfB);
  fc_kernel<<<dim3(128, 8), dim3(256), 0, stream>>>(
      hsfF, hsfB, wfcpack, bfc, out);
}